// Round 4
// baseline (1781.653 us; speedup 1.0000x reference)
//
#include <hip/hip_runtime.h>
#include <hip/hip_bf16.h>

#define NLAYERS 6
#define Bc 2
#define Tc 13294
#define Ec 256
#define NHc 8
#define FFNc 1024

#define EPI_BIAS 0
#define EPI_MASK 1
#define EPI_RES  2
#define EPI_RELU 3

typedef __attribute__((ext_vector_type(8))) short bf16x8;
typedef __attribute__((ext_vector_type(4))) float f32x4;

typedef __attribute__((address_space(3))) unsigned int u32_lds;
typedef __attribute__((address_space(1))) unsigned int u32_glb;

__device__ __forceinline__ void gld16(const void* g, void* l) {
    __builtin_amdgcn_global_load_lds((const u32_glb*)g, (u32_lds*)l, 16, 0, 0);
}

__device__ __forceinline__ short f2bf(float f) {
    union { float f; unsigned u; } v; v.f = f;
    unsigned r = v.u + 0x7FFFu + ((v.u >> 16) & 1u);
    return (short)(r >> 16);
}

// ---------------- LayerNorm (+ optional q = x + pos), bf16 outputs ----------------
__global__ __launch_bounds__(256) void ln_kernel(
    const float* __restrict__ src, const float* __restrict__ pos,
    const float* __restrict__ g, const float* __restrict__ b,
    short* __restrict__ x, short* __restrict__ q, int rows)
{
    int wave = threadIdx.x >> 6;
    int lane = threadIdx.x & 63;
    int row = blockIdx.x * 4 + wave;
    if (row >= rows) return;
    const float* p = src + (size_t)row * Ec;
    float4 v = *(const float4*)(p + lane * 4);
    float s  = v.x + v.y + v.z + v.w;
    float sq = v.x*v.x + v.y*v.y + v.z*v.z + v.w*v.w;
    #pragma unroll
    for (int o = 32; o; o >>= 1) { s += __shfl_xor(s, o); sq += __shfl_xor(sq, o); }
    float mean = s * (1.f / Ec);
    float var  = sq * (1.f / Ec) - mean * mean;
    float inv  = rsqrtf(var + 1e-5f);
    float4 gg = *(const float4*)(g + lane * 4);
    float4 bb = *(const float4*)(b + lane * 4);
    float xo0 = (v.x - mean) * inv * gg.x + bb.x;
    float xo1 = (v.y - mean) * inv * gg.y + bb.y;
    float xo2 = (v.z - mean) * inv * gg.z + bb.z;
    float xo3 = (v.w - mean) * inv * gg.w + bb.w;
    short4 xs; xs.x = f2bf(xo0); xs.y = f2bf(xo1); xs.z = f2bf(xo2); xs.w = f2bf(xo3);
    *(short4*)(x + (size_t)row * Ec + lane * 4) = xs;
    if (q) {
        float4 pp = *(const float4*)(pos + (size_t)row * Ec + lane * 4);
        short4 qs;
        qs.x = f2bf(xo0 + pp.x); qs.y = f2bf(xo1 + pp.y);
        qs.z = f2bf(xo2 + pp.z); qs.w = f2bf(xo3 + pp.w);
        *(short4*)(q + (size_t)row * Ec + lane * 4) = qs;
    }
}

// ---------------- weight transpose+convert: W[K][N] fp32 -> Wt[rowOff+N][K] bf16 ----------------
__global__ __launch_bounds__(256) void transpose_w(
    const float* __restrict__ W, short* __restrict__ Wt, int K, int N,
    int layerStride, int rowOff)
{
    __shared__ float tile[32][33];
    int l = blockIdx.z;
    const float* Wl = W + (size_t)l * K * N;
    short* Wtl = Wt + (size_t)l * layerStride;
    int n0 = blockIdx.x * 32, k0 = blockIdx.y * 32;
    int tx = threadIdx.x & 31, ty = threadIdx.x >> 5;
    #pragma unroll
    for (int i = 0; i < 32; i += 8)
        tile[ty + i][tx] = Wl[(size_t)(k0 + ty + i) * N + n0 + tx];
    __syncthreads();
    #pragma unroll
    for (int i = 0; i < 32; i += 8)
        Wtl[(size_t)(rowOff + n0 + ty + i) * K + k0 + tx] = f2bf(tile[tx][ty + i]);
}

// ---------------- bf16 MFMA GEMM: 128x128 tile, BK=32, double-buffered LDS ----------------
// A: MxK bf16 row-major; Bt: NxK bf16 (pre-transposed); global_load_lds staging, linear LDS.
// 2-phase schedule: stage(t+1) issued BEFORE compute(t); barrier drains vmcnt.
template<int EPI, int OBF>
__global__ __launch_bounds__(256) void gemm_mfma(
    const short* __restrict__ A, const short* __restrict__ Bt,
    const float* __restrict__ bias, const float* __restrict__ bias2,
    const float* __restrict__ res, const unsigned char* __restrict__ mask,
    void* __restrict__ Cout, int M, int N, int K)
{
    __shared__ short As[2][128 * 32];
    __shared__ short Bs[2][128 * 32];
    const int tid = threadIdx.x;
    const int lane = tid & 63;
    const int wv = tid >> 6;
    const int row0 = blockIdx.x * 128;
    const int col0 = blockIdx.y * 128;
    const int mbase = (wv >> 1) * 64;
    const int nbase = (wv & 1) * 64;
    const int lr = lane & 15;
    const int kg = lane >> 4;

    f32x4 zf = {0.f, 0.f, 0.f, 0.f};
    f32x4 acc[4][4];
    #pragma unroll
    for (int i = 0; i < 4; ++i)
        #pragma unroll
        for (int j = 0; j < 4; ++j) acc[i][j] = zf;

    // staging: wave wv stages rows [wv*32, wv*32+32); lane l -> row wv*32(+16)+l/4, col (l%4)*8
    const int srow = wv * 32 + (lane >> 2);
    const int scol = (lane & 3) * 8;
    const short* Ap  = A  + (size_t)(row0 + srow) * K + scol;
    const short* Bp  = Bt + (size_t)(col0 + srow) * K + scol;
    const int l0 = srow * 32 + scol;
    const int l1 = l0 + 16 * 32;

    #define STAGE(buf, k0) do { \
        gld16(Ap + (k0),               &As[buf][l0]); \
        gld16(Ap + (size_t)16*K + (k0), &As[buf][l1]); \
        gld16(Bp + (k0),               &Bs[buf][l0]); \
        gld16(Bp + (size_t)16*K + (k0), &Bs[buf][l1]); \
    } while (0)

    STAGE(0, 0);
    __syncthreads();
    int cur = 0;
    for (int k0 = 0; k0 < K; k0 += 32) {
        if (k0 + 32 < K) STAGE(cur ^ 1, k0 + 32);
        bf16x8 af[4], bfr[4];
        #pragma unroll
        for (int i = 0; i < 4; ++i) {
            af[i]  = *(const bf16x8*)&As[cur][(mbase + i * 16 + lr) * 32 + kg * 8];
            bfr[i] = *(const bf16x8*)&Bs[cur][(nbase + i * 16 + lr) * 32 + kg * 8];
        }
        #pragma unroll
        for (int mi = 0; mi < 4; ++mi)
            #pragma unroll
            for (int ni = 0; ni < 4; ++ni)
                acc[mi][ni] = __builtin_amdgcn_mfma_f32_16x16x32_bf16(
                    af[mi], bfr[ni], acc[mi][ni], 0, 0, 0);
        __syncthreads();
        cur ^= 1;
    }
    #undef STAGE

    float* Cf = (float*)Cout;
    short* Cb = (short*)Cout;
    #pragma unroll
    for (int ni = 0; ni < 4; ++ni) {
        int col = col0 + nbase + ni * 16 + lr;
        float bz = (bias2 && col >= 256) ? bias2[col - 256] : bias[col];
        #pragma unroll
        for (int mi = 0; mi < 4; ++mi) {
            int rb = row0 + mbase + mi * 16 + kg * 4;
            #pragma unroll
            for (int j = 0; j < 4; ++j) {
                int grow = rb + j;
                if (grow >= M) continue;
                float v = acc[mi][ni][j] + bz;
                if (EPI == EPI_MASK) { if (mask[grow]) v = 0.f; }
                if (EPI == EPI_RES)  v += res[(size_t)grow * N + col];
                if (EPI == EPI_RELU) v = v > 0.f ? v : 0.f;
                if (OBF) Cb[(size_t)grow * N + col] = f2bf(v);
                else     Cf[(size_t)grow * N + col] = v;
            }
        }
    }
}

// ---------------- MSDA with fused softmax; value is fp32 ----------------
// group = 32 lanes = one (b,q,h); 8 groups/block.
// pts LDS: group stride 136 words (544B, +8 banks); point slot = p*8 + ((p>>3)&1)*4 words
// (XOR 16B for p>=8, +4 banks) -> the wave's 4 distinct b128 reads start at banks {0,4,8,12}.
__global__ __launch_bounds__(256) void msda_kernel(
    const float* __restrict__ value, const float* __restrict__ oa,
    const float* __restrict__ vr, short* __restrict__ out)
{
    __shared__ int pts[8 * 136];
    const int group = threadIdx.x >> 5;
    const int l32 = threadIdx.x & 31;
    const int gidx = blockIdx.x * 8 + group;
    const int h = gidx & 7;
    const int bq = gidx >> 3;
    const int b = (bq >= Tc) ? 1 : 0;
    const int qq = bq - b * Tc;

    if (l32 < 16) {
        const int p = l32;
        const int lvl = p >> 2;
        const int Wl[4] = {100, 50, 25, 13};
        const int St[4] = {0, 10000, 12500, 13125};
        float base_x, base_y;
        if (qq < 10000) {
            int qi = qq;
            base_x = (0.5f + (float)(qi % 100)) / (vr[(b*4+0)*2+0] * 100.f);
            base_y = (0.5f + (float)(qi / 100)) / (vr[(b*4+0)*2+1] * 100.f);
        } else if (qq < 12500) {
            int qi = qq - 10000;
            base_x = (0.5f + (float)(qi % 50)) / (vr[(b*4+1)*2+0] * 50.f);
            base_y = (0.5f + (float)(qi / 50)) / (vr[(b*4+1)*2+1] * 50.f);
        } else if (qq < 13125) {
            int qi = qq - 12500;
            base_x = (0.5f + (float)(qi % 25)) / (vr[(b*4+2)*2+0] * 25.f);
            base_y = (0.5f + (float)(qi / 25)) / (vr[(b*4+2)*2+1] * 25.f);
        } else {
            int qi = qq - 13125;
            base_x = (0.5f + (float)(qi % 13)) / (vr[(b*4+3)*2+0] * 13.f);
            base_y = (0.5f + (float)(qi / 13)) / (vr[(b*4+3)*2+1] * 13.f);
        }
        // softmax over 16 logits (one per lane)
        float logit = oa[(size_t)bq * 384 + 256 + h * 16 + p];
        float mx = logit;
        #pragma unroll
        for (int o = 8; o; o >>= 1) mx = fmaxf(mx, __shfl_xor(mx, o));
        float e = expf(logit - mx);
        float sum = e;
        #pragma unroll
        for (int o = 8; o; o >>= 1) sum += __shfl_xor(sum, o);
        float aw = e / sum;

        const int w = Wl[lvl], hh = Wl[lvl];
        const float refx = base_x * vr[(b*4+lvl)*2+0];
        const float refy = base_y * vr[(b*4+lvl)*2+1];
        const float ox = oa[(size_t)bq * 384 + h * 32 + p * 2 + 0];
        const float oy = oa[(size_t)bq * 384 + h * 32 + p * 2 + 1];
        float locx = refx + ox / (float)w;
        float locy = refy + oy / (float)hh;
        float xf = locx * (float)w - 0.5f;
        float yf = locy * (float)hh - 0.5f;
        float x0f = floorf(xf), y0f = floorf(yf);
        int x0 = (int)x0f, y0 = (int)y0f;
        float wx = xf - x0f, wy = yf - y0f;
        float w00 = (1.f - wx) * (1.f - wy) * aw;
        float w10 = wx * (1.f - wy) * aw;
        float w01 = (1.f - wx) * wy * aw;
        float w11 = wx * wy * aw;
        bool vx0 = (x0 >= 0) && (x0 < w);
        bool vx1 = (x0 + 1 >= 0) && (x0 + 1 < w);
        bool vy0 = (y0 >= 0) && (y0 < hh);
        bool vy1 = (y0 + 1 >= 0) && (y0 + 1 < hh);
        if (!(vx0 && vy0)) w00 = 0.f;
        if (!(vx1 && vy0)) w10 = 0.f;
        if (!(vx0 && vy1)) w01 = 0.f;
        if (!(vx1 && vy1)) w11 = 0.f;
        int cx0 = min(max(x0, 0), w - 1), cx1 = min(max(x0 + 1, 0), w - 1);
        int cy0 = min(max(y0, 0), hh - 1), cy1 = min(max(y0 + 1, 0), hh - 1);
        int rowbase = b * Tc + St[lvl];
        int slot = group * 136 + p * 8 + ((p >> 3) & 1) * 4;
        int4 wq4; wq4.x = __float_as_int(w00); wq4.y = __float_as_int(w10);
        wq4.z = __float_as_int(w01); wq4.w = __float_as_int(w11);
        // byte offsets of the (row, h) 128B fp32 slice for each corner
        int4 aq4;
        aq4.x = (rowbase + cy0 * w + cx0) * 1024 + h * 128;
        aq4.y = (rowbase + cy0 * w + cx1) * 1024 + h * 128;
        aq4.z = (rowbase + cy1 * w + cx0) * 1024 + h * 128;
        aq4.w = (rowbase + cy1 * w + cx1) * 1024 + h * 128;
        *(int4*)&pts[slot] = wq4;
        *(int4*)&pts[slot + 4] = aq4;
    }
    __syncthreads();

    const int d8 = (l32 & 15) * 8;          // byte offset of this lane's fp32 dim pair
    const int ph = (l32 >> 4) * 8;          // lanes 0-15: points 0-7; lanes 16-31: 8-15
    const int xw = (l32 >> 4) * 4;          // slot XOR word-shift for p>=8
    const char* vbase = (const char*)value;
    float accL = 0.f, accH = 0.f;
    #pragma unroll
    for (int j = 0; j < 8; ++j) {
        int p = ph + j;
        int slot = group * 136 + p * 8 + xw;
        int4 wq = *(const int4*)&pts[slot];
        int4 aq = *(const int4*)&pts[slot + 4];
        float2 v0 = *(const float2*)(vbase + (unsigned)(aq.x + d8));
        float2 v1 = *(const float2*)(vbase + (unsigned)(aq.y + d8));
        float2 v2 = *(const float2*)(vbase + (unsigned)(aq.z + d8));
        float2 v3 = *(const float2*)(vbase + (unsigned)(aq.w + d8));
        float w00 = __int_as_float(wq.x), w10 = __int_as_float(wq.y);
        float w01 = __int_as_float(wq.z), w11 = __int_as_float(wq.w);
        accL = fmaf(w00, v0.x, accL); accH = fmaf(w00, v0.y, accH);
        accL = fmaf(w10, v1.x, accL); accH = fmaf(w10, v1.y, accH);
        accL = fmaf(w01, v2.x, accL); accH = fmaf(w01, v2.y, accH);
        accL = fmaf(w11, v3.x, accL); accH = fmaf(w11, v3.y, accH);
    }
    accL += __shfl_xor(accL, 16);
    accH += __shfl_xor(accH, 16);
    if (l32 < 16) {
        unsigned pk = ((unsigned)(unsigned short)f2bf(accL)) |
                      (((unsigned)(unsigned short)f2bf(accH)) << 16);
        *(unsigned*)((char*)out + (size_t)bq * 512 + h * 64 + (l32 & 15) * 4) = pk;
    }
}

extern "C" void kernel_launch(void* const* d_in, const int* in_sizes, int n_in,
                              void* d_out, int out_size, void* d_ws, size_t ws_size,
                              hipStream_t stream) {
    const float* src  = (const float*)d_in[0];
    const float* pos  = (const float*)d_in[1];
    const float* vr   = (const float*)d_in[2];
    const unsigned char* mask = (const unsigned char*)d_in[5];
    const float* Wv    = (const float*)d_in[6];
    const float* bv    = (const float*)d_in[7];
    const float* Woff  = (const float*)d_in[8];
    const float* boff  = (const float*)d_in[9];
    const float* Wattn = (const float*)d_in[10];
    const float* battn = (const float*)d_in[11];
    const float* Wout  = (const float*)d_in[12];
    const float* bout  = (const float*)d_in[13];
    const float* n1g   = (const float*)d_in[14];
    const float* n1b   = (const float*)d_in[15];
    const float* n2g   = (const float*)d_in[16];
    const float* n2b   = (const float*)d_in[17];
    const float* W1    = (const float*)d_in[18];
    const float* b1    = (const float*)d_in[19];
    const float* W2    = (const float*)d_in[20];
    const float* b2    = (const float*)d_in[21];
    float* out = (float*)d_out;

    const size_t R = (size_t)Bc * Tc;   // 26588

    // layout (bytes): xb R*512 | qb R*512 | valf R*1024 | msdab R*512 | oab R*1536 | srcb R*1024 | weights
    short* xb    = (short*)d_ws;              // R*256 bf16
    short* qb    = xb + R * 256;              // R*256 bf16
    float* valf  = (float*)(qb + R * 256);    // R*256 f32
    short* msdab = (short*)(valf + R * 256);  // R*256 bf16
    short* ln2b  = xb;                        // alias: xb dead by LN2
    short* hb    = qb;                        // alias: qb..msdab = R*1024 bf16, dead by FFN1
    float* oab   = (float*)(msdab + R * 256); // R*384 f32 (off 256 | logits 128)
    float* srcb  = oab + R * 384;             // R*256 f32
    short* wvT   = (short*)(srcb + R * 256);  // 6*65536
    short* woaT  = wvT + 6 * 65536;           // 6*98304 ([384][256])
    short* woutT = woaT + 6 * 98304;          // 6*65536
    short* w1T   = woutT + 6 * 65536;         // 6*262144 ([1024][256])
    short* w2T   = w1T + 6 * 262144;          // 6*262144 ([256][1024])

    // one-time weight transpose+convert (grid: x=N/32, y=K/32, z=layers)
    transpose_w<<<dim3(8, 8, 6),  256, 0, stream>>>(Wv,    wvT,   256, 256,  65536, 0);
    transpose_w<<<dim3(8, 8, 6),  256, 0, stream>>>(Woff,  woaT,  256, 256,  98304, 0);
    transpose_w<<<dim3(4, 8, 6),  256, 0, stream>>>(Wattn, woaT,  256, 128,  98304, 256);
    transpose_w<<<dim3(8, 8, 6),  256, 0, stream>>>(Wout,  woutT, 256, 256,  65536, 0);
    transpose_w<<<dim3(32, 8, 6), 256, 0, stream>>>(W1,    w1T,   256, 1024, 262144, 0);
    transpose_w<<<dim3(8, 32, 6), 256, 0, stream>>>(W2,    w2T,   1024, 256, 262144, 0);

    const int lnBlocks = (int)((R + 3) / 4);
    const int MT = (int)((R + 127) / 128);  // 208

    for (int l = 0; l < NLAYERS; ++l) {
        const float* cur = (l == 0) ? src : srcb;
        // LN1 -> x (bf16), q = x + pos (bf16)
        ln_kernel<<<lnBlocks, 256, 0, stream>>>(cur, pos, n1g + l * Ec, n1b + l * Ec, xb, qb, (int)R);
        // value = x @ Wv + bv, mask->0 (fp32 out)
        gemm_mfma<EPI_MASK, 0><<<dim3(MT, 2), 256, 0, stream>>>(
            xb, wvT + (size_t)l * 65536, bv + l * Ec, nullptr, nullptr, mask, valf, (int)R, 256, 256);
        // [off | attn logits] = q @ [Woff|Wattn] + [boff|battn] (fp32, N=384)
        gemm_mfma<EPI_BIAS, 0><<<dim3(MT, 3), 256, 0, stream>>>(
            qb, woaT + (size_t)l * 98304, boff + l * 256, battn + l * 128, nullptr, nullptr,
            oab, (int)R, 384, 256);
        // MSDA (softmax fused) -> bf16
        msda_kernel<<<(int)R, 256, 0, stream>>>(valf, oab, vr, msdab);
        // src2 = src + msda @ Wout + bout (fp32)
        gemm_mfma<EPI_RES, 0><<<dim3(MT, 2), 256, 0, stream>>>(
            msdab, woutT + (size_t)l * 65536, bout + l * Ec, nullptr, cur, nullptr, srcb, (int)R, 256, 256);
        // LN2 -> bf16
        ln_kernel<<<lnBlocks, 256, 0, stream>>>(srcb, nullptr, n2g + l * Ec, n2b + l * Ec, ln2b, nullptr, (int)R);
        // h = relu(x2 @ W1 + b1) (bf16)
        gemm_mfma<EPI_RELU, 1><<<dim3(MT, 8), 256, 0, stream>>>(
            ln2b, w1T + (size_t)l * 262144, b1 + l * FFNc, nullptr, nullptr, nullptr, hb, (int)R, 1024, 256);
        // out = src2 + h @ W2 + b2 (fp32)
        float* dst = (l == NLAYERS - 1) ? out : srcb;
        gemm_mfma<EPI_RES, 0><<<dim3(MT, 2), 256, 0, stream>>>(
            hb, w2T + (size_t)l * 262144, b2 + l * Ec, nullptr, srcb, nullptr, dst, (int)R, 256, 1024);
    }
}

// Round 5
// 1250.047 us; speedup vs baseline: 1.4253x; 1.4253x over previous
//
#include <hip/hip_runtime.h>
#include <hip/hip_bf16.h>

#define NLAYERS 6
#define Bc 2
#define Tc 13294
#define Ec 256
#define NHc 8
#define FFNc 1024

#define EPI_BIAS 0
#define EPI_MASK 1
#define EPI_RES  2
#define EPI_RELU 3

typedef __attribute__((ext_vector_type(8))) short bf16x8;
typedef __attribute__((ext_vector_type(4))) float f32x4;

typedef __attribute__((address_space(3))) unsigned int u32_lds;
typedef __attribute__((address_space(1))) unsigned int u32_glb;

__device__ __forceinline__ void gld16(const void* g, void* l) {
    __builtin_amdgcn_global_load_lds((const u32_glb*)g, (u32_lds*)l, 16, 0, 0);
}

__device__ __forceinline__ short f2bf(float f) {
    union { float f; unsigned u; } v; v.f = f;
    unsigned r = v.u + 0x7FFFu + ((v.u >> 16) & 1u);
    return (short)(r >> 16);
}
__device__ __forceinline__ float bf2f(short s) {
    union { unsigned u; float f; } v; v.u = ((unsigned)(unsigned short)s) << 16;
    return v.f;
}
__device__ __forceinline__ float bf_lo(unsigned u) {
    union { unsigned u; float f; } v; v.u = u << 16; return v.f;
}
__device__ __forceinline__ float bf_hi(unsigned u) {
    union { unsigned u; float f; } v; v.u = u & 0xFFFF0000u; return v.f;
}

// ---------------- LayerNorm (+ optional q = x + pos), bf16 outputs ----------------
__global__ __launch_bounds__(256) void ln_kernel(
    const float* __restrict__ src, const float* __restrict__ pos,
    const float* __restrict__ g, const float* __restrict__ b,
    short* __restrict__ x, short* __restrict__ q, int rows)
{
    int wave = threadIdx.x >> 6;
    int lane = threadIdx.x & 63;
    int row = blockIdx.x * 4 + wave;
    if (row >= rows) return;
    const float* p = src + (size_t)row * Ec;
    float4 v = *(const float4*)(p + lane * 4);
    float s  = v.x + v.y + v.z + v.w;
    float sq = v.x*v.x + v.y*v.y + v.z*v.z + v.w*v.w;
    #pragma unroll
    for (int o = 32; o; o >>= 1) { s += __shfl_xor(s, o); sq += __shfl_xor(sq, o); }
    float mean = s * (1.f / Ec);
    float var  = sq * (1.f / Ec) - mean * mean;
    float inv  = rsqrtf(var + 1e-5f);
    float4 gg = *(const float4*)(g + lane * 4);
    float4 bb = *(const float4*)(b + lane * 4);
    float xo0 = (v.x - mean) * inv * gg.x + bb.x;
    float xo1 = (v.y - mean) * inv * gg.y + bb.y;
    float xo2 = (v.z - mean) * inv * gg.z + bb.z;
    float xo3 = (v.w - mean) * inv * gg.w + bb.w;
    short4 xs; xs.x = f2bf(xo0); xs.y = f2bf(xo1); xs.z = f2bf(xo2); xs.w = f2bf(xo3);
    *(short4*)(x + (size_t)row * Ec + lane * 4) = xs;
    if (q) {
        float4 pp = *(const float4*)(pos + (size_t)row * Ec + lane * 4);
        short4 qs;
        qs.x = f2bf(xo0 + pp.x); qs.y = f2bf(xo1 + pp.y);
        qs.z = f2bf(xo2 + pp.z); qs.w = f2bf(xo3 + pp.w);
        *(short4*)(q + (size_t)row * Ec + lane * 4) = qs;
    }
}

// ---------------- weight transpose+convert: W[K][N] fp32 -> Wt[rowOff+N][K] bf16 ----------------
__global__ __launch_bounds__(256) void transpose_w(
    const float* __restrict__ W, short* __restrict__ Wt, int K, int N,
    int layerStride, int rowOff)
{
    __shared__ float tile[32][33];
    int l = blockIdx.z;
    const float* Wl = W + (size_t)l * K * N;
    short* Wtl = Wt + (size_t)l * layerStride;
    int n0 = blockIdx.x * 32, k0 = blockIdx.y * 32;
    int tx = threadIdx.x & 31, ty = threadIdx.x >> 5;
    #pragma unroll
    for (int i = 0; i < 32; i += 8)
        tile[ty + i][tx] = Wl[(size_t)(k0 + ty + i) * N + n0 + tx];
    __syncthreads();
    #pragma unroll
    for (int i = 0; i < 32; i += 8)
        Wtl[(size_t)(rowOff + n0 + ty + i) * K + k0 + tx] = f2bf(tile[tx][ty + i]);
}

// ---------------- bf16 MFMA GEMM: 128x64 tile, BK=32, double-buffered LDS ----------------
// A: MxK bf16 row-major; Bt: NxK bf16 (pre-transposed); global_load_lds, linear LDS.
// 2-phase: STAGE(t+1) issued BEFORE compute(t); barrier drains vmcnt.
template<int EPI, int OBF>
__global__ __launch_bounds__(256) void gemm_mfma(
    const short* __restrict__ A, const short* __restrict__ Bt,
    const float* __restrict__ bias, const float* __restrict__ bias2,
    const float* __restrict__ res, const unsigned char* __restrict__ mask,
    void* __restrict__ Cout, int M, int N, int K)
{
    __shared__ short As[2][128 * 32];
    __shared__ short Bs[2][64 * 32];
    const int tid = threadIdx.x;
    const int lane = tid & 63;
    const int wv = tid >> 6;
    const int row0 = blockIdx.x * 128;
    const int col0 = blockIdx.y * 64;
    const int mbase = (wv >> 1) * 64;   // wave tile: 64 rows x 32 cols
    const int nbase = (wv & 1) * 32;
    const int lr = lane & 15;
    const int kg = lane >> 4;

    f32x4 zf = {0.f, 0.f, 0.f, 0.f};
    f32x4 acc[4][2];
    #pragma unroll
    for (int i = 0; i < 4; ++i)
        #pragma unroll
        for (int j = 0; j < 2; ++j) acc[i][j] = zf;

    // A staging: wave wv stages rows [wv*32, wv*32+32); lane l -> row wv*32(+16)+l/4, col (l%4)*8
    const int scol = (lane & 3) * 8;
    const int srowA = wv * 32 + (lane >> 2);
    const short* Ap = A + (size_t)(row0 + srowA) * K + scol;
    const int lA0 = srowA * 32 + scol;
    const int lA1 = lA0 + 16 * 32;
    // B staging: wave wv stages rows [wv*16, wv*16+16)
    const int srowB = wv * 16 + (lane >> 2);
    const short* Bp = Bt + (size_t)(col0 + srowB) * K + scol;
    const int lB = srowB * 32 + scol;

    #define STAGE(buf, k0) do { \
        gld16(Ap + (k0),                &As[buf][lA0]); \
        gld16(Ap + (size_t)16*K + (k0), &As[buf][lA1]); \
        gld16(Bp + (k0),                &Bs[buf][lB]); \
    } while (0)

    STAGE(0, 0);
    __syncthreads();
    int cur = 0;
    for (int k0 = 0; k0 < K; k0 += 32) {
        if (k0 + 32 < K) STAGE(cur ^ 1, k0 + 32);
        bf16x8 af[4], bfr[2];
        #pragma unroll
        for (int i = 0; i < 4; ++i)
            af[i]  = *(const bf16x8*)&As[cur][(mbase + i * 16 + lr) * 32 + kg * 8];
        #pragma unroll
        for (int j = 0; j < 2; ++j)
            bfr[j] = *(const bf16x8*)&Bs[cur][(nbase + j * 16 + lr) * 32 + kg * 8];
        #pragma unroll
        for (int mi = 0; mi < 4; ++mi)
            #pragma unroll
            for (int ni = 0; ni < 2; ++ni)
                acc[mi][ni] = __builtin_amdgcn_mfma_f32_16x16x32_bf16(
                    af[mi], bfr[ni], acc[mi][ni], 0, 0, 0);
        __syncthreads();
        cur ^= 1;
    }
    #undef STAGE

    float* Cf = (float*)Cout;
    short* Cb = (short*)Cout;
    #pragma unroll
    for (int ni = 0; ni < 2; ++ni) {
        int col = col0 + nbase + ni * 16 + lr;
        float bz = (bias2 && col >= 256) ? bias2[col - 256] : bias[col];
        #pragma unroll
        for (int mi = 0; mi < 4; ++mi) {
            int rb = row0 + mbase + mi * 16 + kg * 4;
            #pragma unroll
            for (int j = 0; j < 4; ++j) {
                int grow = rb + j;
                if (grow >= M) continue;
                float v = acc[mi][ni][j] + bz;
                if (EPI == EPI_MASK) { if (mask[grow]) v = 0.f; }
                if (EPI == EPI_RES)  v += res[(size_t)grow * N + col];
                if (EPI == EPI_RELU) v = v > 0.f ? v : 0.f;
                if (OBF) Cb[(size_t)grow * N + col] = f2bf(v);
                else     Cf[(size_t)grow * N + col] = v;
            }
        }
    }
}

// ---------------- MSDA with fused softmax; value + oa are bf16 ----------------
// group = 32 lanes = one (b,q,h); 8 groups/block.
// pts LDS: group stride 136 words; point slot = p*8 + ((p>>3)&1)*4 words
// -> the wave's 4 distinct b128 read-starts land on banks {0,4,8,12}: conflict-free.
__global__ __launch_bounds__(256) void msda_kernel(
    const short* __restrict__ value, const short* __restrict__ oa,
    const float* __restrict__ vr, short* __restrict__ out)
{
    __shared__ int pts[8 * 136];
    const int group = threadIdx.x >> 5;
    const int l32 = threadIdx.x & 31;
    const int gidx = blockIdx.x * 8 + group;
    const int h = gidx & 7;
    const int bq = gidx >> 3;
    const int b = (bq >= Tc) ? 1 : 0;
    const int qq = bq - b * Tc;

    if (l32 < 16) {
        const int p = l32;
        const int lvl = p >> 2;
        const int Wl[4] = {100, 50, 25, 13};
        const int St[4] = {0, 10000, 12500, 13125};
        float base_x, base_y;
        if (qq < 10000) {
            int qi = qq;
            base_x = (0.5f + (float)(qi % 100)) / (vr[(b*4+0)*2+0] * 100.f);
            base_y = (0.5f + (float)(qi / 100)) / (vr[(b*4+0)*2+1] * 100.f);
        } else if (qq < 12500) {
            int qi = qq - 10000;
            base_x = (0.5f + (float)(qi % 50)) / (vr[(b*4+1)*2+0] * 50.f);
            base_y = (0.5f + (float)(qi / 50)) / (vr[(b*4+1)*2+1] * 50.f);
        } else if (qq < 13125) {
            int qi = qq - 12500;
            base_x = (0.5f + (float)(qi % 25)) / (vr[(b*4+2)*2+0] * 25.f);
            base_y = (0.5f + (float)(qi / 25)) / (vr[(b*4+2)*2+1] * 25.f);
        } else {
            int qi = qq - 13125;
            base_x = (0.5f + (float)(qi % 13)) / (vr[(b*4+3)*2+0] * 13.f);
            base_y = (0.5f + (float)(qi / 13)) / (vr[(b*4+3)*2+1] * 13.f);
        }
        // softmax over 16 logits (one per lane)
        float logit = bf2f(oa[(size_t)bq * 384 + 256 + h * 16 + p]);
        float mx = logit;
        #pragma unroll
        for (int o = 8; o; o >>= 1) mx = fmaxf(mx, __shfl_xor(mx, o));
        float e = expf(logit - mx);
        float sum = e;
        #pragma unroll
        for (int o = 8; o; o >>= 1) sum += __shfl_xor(sum, o);
        float aw = e / sum;

        const int w = Wl[lvl], hh = Wl[lvl];
        const float refx = base_x * vr[(b*4+lvl)*2+0];
        const float refy = base_y * vr[(b*4+lvl)*2+1];
        const float ox = bf2f(oa[(size_t)bq * 384 + h * 32 + p * 2 + 0]);
        const float oy = bf2f(oa[(size_t)bq * 384 + h * 32 + p * 2 + 1]);
        float locx = refx + ox / (float)w;
        float locy = refy + oy / (float)hh;
        float xf = locx * (float)w - 0.5f;
        float yf = locy * (float)hh - 0.5f;
        float x0f = floorf(xf), y0f = floorf(yf);
        int x0 = (int)x0f, y0 = (int)y0f;
        float wx = xf - x0f, wy = yf - y0f;
        float w00 = (1.f - wx) * (1.f - wy) * aw;
        float w10 = wx * (1.f - wy) * aw;
        float w01 = (1.f - wx) * wy * aw;
        float w11 = wx * wy * aw;
        bool vx0 = (x0 >= 0) && (x0 < w);
        bool vx1 = (x0 + 1 >= 0) && (x0 + 1 < w);
        bool vy0 = (y0 >= 0) && (y0 < hh);
        bool vy1 = (y0 + 1 >= 0) && (y0 + 1 < hh);
        if (!(vx0 && vy0)) w00 = 0.f;
        if (!(vx1 && vy0)) w10 = 0.f;
        if (!(vx0 && vy1)) w01 = 0.f;
        if (!(vx1 && vy1)) w11 = 0.f;
        int cx0 = min(max(x0, 0), w - 1), cx1 = min(max(x0 + 1, 0), w - 1);
        int cy0 = min(max(y0, 0), hh - 1), cy1 = min(max(y0 + 1, 0), hh - 1);
        int rowbase = b * Tc + St[lvl];
        int slot = group * 136 + p * 8 + ((p >> 3) & 1) * 4;
        int4 wq4; wq4.x = __float_as_int(w00); wq4.y = __float_as_int(w10);
        wq4.z = __float_as_int(w01); wq4.w = __float_as_int(w11);
        // byte offsets of the (row, h) 64B bf16 slice for each corner
        int4 aq4;
        aq4.x = (rowbase + cy0 * w + cx0) * 512 + h * 64;
        aq4.y = (rowbase + cy0 * w + cx1) * 512 + h * 64;
        aq4.z = (rowbase + cy1 * w + cx0) * 512 + h * 64;
        aq4.w = (rowbase + cy1 * w + cx1) * 512 + h * 64;
        *(int4*)&pts[slot] = wq4;
        *(int4*)&pts[slot + 4] = aq4;
    }
    __syncthreads();

    const int d4 = (l32 & 15) * 4;          // byte offset of this lane's bf16 dim pair
    const int ph = (l32 >> 4) * 8;          // lanes 0-15: points 0-7; lanes 16-31: 8-15
    const int xw = (l32 >> 4) * 4;          // slot word-shift for p>=8
    const char* vbase = (const char*)value;
    float accL = 0.f, accH = 0.f;
    #pragma unroll
    for (int j = 0; j < 8; ++j) {
        int p = ph + j;
        int slot = group * 136 + p * 8 + xw;
        int4 wq = *(const int4*)&pts[slot];
        int4 aq = *(const int4*)&pts[slot + 4];
        unsigned u0 = *(const unsigned*)(vbase + (unsigned)(aq.x + d4));
        unsigned u1 = *(const unsigned*)(vbase + (unsigned)(aq.y + d4));
        unsigned u2 = *(const unsigned*)(vbase + (unsigned)(aq.z + d4));
        unsigned u3 = *(const unsigned*)(vbase + (unsigned)(aq.w + d4));
        float w00 = __int_as_float(wq.x), w10 = __int_as_float(wq.y);
        float w01 = __int_as_float(wq.z), w11 = __int_as_float(wq.w);
        accL = fmaf(w00, bf_lo(u0), accL); accH = fmaf(w00, bf_hi(u0), accH);
        accL = fmaf(w10, bf_lo(u1), accL); accH = fmaf(w10, bf_hi(u1), accH);
        accL = fmaf(w01, bf_lo(u2), accL); accH = fmaf(w01, bf_hi(u2), accH);
        accL = fmaf(w11, bf_lo(u3), accL); accH = fmaf(w11, bf_hi(u3), accH);
    }
    accL += __shfl_xor(accL, 16);
    accH += __shfl_xor(accH, 16);
    if (l32 < 16) {
        unsigned pk = ((unsigned)(unsigned short)f2bf(accL)) |
                      (((unsigned)(unsigned short)f2bf(accH)) << 16);
        *(unsigned*)((char*)out + (size_t)bq * 512 + h * 64 + d4) = pk;
    }
}

extern "C" void kernel_launch(void* const* d_in, const int* in_sizes, int n_in,
                              void* d_out, int out_size, void* d_ws, size_t ws_size,
                              hipStream_t stream) {
    const float* src  = (const float*)d_in[0];
    const float* pos  = (const float*)d_in[1];
    const float* vr   = (const float*)d_in[2];
    const unsigned char* mask = (const unsigned char*)d_in[5];
    const float* Wv    = (const float*)d_in[6];
    const float* bv    = (const float*)d_in[7];
    const float* Woff  = (const float*)d_in[8];
    const float* boff  = (const float*)d_in[9];
    const float* Wattn = (const float*)d_in[10];
    const float* battn = (const float*)d_in[11];
    const float* Wout  = (const float*)d_in[12];
    const float* bout  = (const float*)d_in[13];
    const float* n1g   = (const float*)d_in[14];
    const float* n1b   = (const float*)d_in[15];
    const float* n2g   = (const float*)d_in[16];
    const float* n2b   = (const float*)d_in[17];
    const float* W1    = (const float*)d_in[18];
    const float* b1    = (const float*)d_in[19];
    const float* W2    = (const float*)d_in[20];
    const float* b2    = (const float*)d_in[21];
    float* out = (float*)d_out;

    const size_t R = (size_t)Bc * Tc;   // 26588

    // bf16 activations (shorts per row): xb 256 | qb 256 | valb 256 | msdab 256 | oab 384
    short* xb    = (short*)d_ws;              // R*256
    short* qb    = xb + R * 256;              // R*256
    short* valb  = qb + R * 256;              // R*256
    short* msdab = valb + R * 256;            // R*256
    short* oab   = msdab + R * 256;           // R*384 (off 256 | logits 128)
    short* ln2b  = xb;                        // alias: xb dead by LN2
    short* hb    = qb;                        // alias: qb..oab >= R*1024, dead by FFN1
    float* srcb  = (float*)(oab + R * 384);   // R*256 f32
    short* wvT   = (short*)(srcb + R * 256);  // 6*65536
    short* woaT  = wvT + 6 * 65536;           // 6*98304 ([384][256])
    short* woutT = woaT + 6 * 98304;          // 6*65536
    short* w1T   = woutT + 6 * 65536;         // 6*262144 ([1024][256])
    short* w2T   = w1T + 6 * 262144;          // 6*262144 ([256][1024])

    // one-time weight transpose+convert (grid: x=N/32, y=K/32, z=layers)
    transpose_w<<<dim3(8, 8, 6),  256, 0, stream>>>(Wv,    wvT,   256, 256,  65536, 0);
    transpose_w<<<dim3(8, 8, 6),  256, 0, stream>>>(Woff,  woaT,  256, 256,  98304, 0);
    transpose_w<<<dim3(4, 8, 6),  256, 0, stream>>>(Wattn, woaT,  256, 128,  98304, 256);
    transpose_w<<<dim3(8, 8, 6),  256, 0, stream>>>(Wout,  woutT, 256, 256,  65536, 0);
    transpose_w<<<dim3(32, 8, 6), 256, 0, stream>>>(W1,    w1T,   256, 1024, 262144, 0);
    transpose_w<<<dim3(8, 32, 6), 256, 0, stream>>>(W2,    w2T,   1024, 256, 262144, 0);

    const int lnBlocks = (int)((R + 3) / 4);
    const int MT = (int)((R + 127) / 128);  // 208

    for (int l = 0; l < NLAYERS; ++l) {
        const float* cur = (l == 0) ? src : srcb;
        // LN1 -> x (bf16), q = x + pos (bf16)
        ln_kernel<<<lnBlocks, 256, 0, stream>>>(cur, pos, n1g + l * Ec, n1b + l * Ec, xb, qb, (int)R);
        // value = x @ Wv + bv, mask->0 (bf16)
        gemm_mfma<EPI_MASK, 1><<<dim3(MT, 4), 256, 0, stream>>>(
            xb, wvT + (size_t)l * 65536, bv + l * Ec, nullptr, nullptr, mask, valb, (int)R, 256, 256);
        // [off | attn logits] = q @ [Woff|Wattn] + [boff|battn] (bf16, N=384)
        gemm_mfma<EPI_BIAS, 1><<<dim3(MT, 6), 256, 0, stream>>>(
            qb, woaT + (size_t)l * 98304, boff + l * 256, battn + l * 128, nullptr, nullptr,
            oab, (int)R, 384, 256);
        // MSDA (softmax fused) -> bf16
        msda_kernel<<<(int)R, 256, 0, stream>>>(valb, oab, vr, msdab);
        // src2 = src + msda @ Wout + bout (fp32)
        gemm_mfma<EPI_RES, 0><<<dim3(MT, 4), 256, 0, stream>>>(
            msdab, woutT + (size_t)l * 65536, bout + l * Ec, nullptr, cur, nullptr, srcb, (int)R, 256, 256);
        // LN2 -> bf16
        ln_kernel<<<lnBlocks, 256, 0, stream>>>(srcb, nullptr, n2g + l * Ec, n2b + l * Ec, ln2b, nullptr, (int)R);
        // h = relu(x2 @ W1 + b1) (bf16)
        gemm_mfma<EPI_RELU, 1><<<dim3(MT, 16), 256, 0, stream>>>(
            ln2b, w1T + (size_t)l * 262144, b1 + l * FFNc, nullptr, nullptr, nullptr, hb, (int)R, 1024, 256);
        // out = src2 + h @ W2 + b2 (fp32)
        float* dst = (l == NLAYERS - 1) ? out : srcb;
        gemm_mfma<EPI_RES, 0><<<dim3(MT, 4), 256, 0, stream>>>(
            hb, w2T + (size_t)l * 262144, b2 + l * Ec, nullptr, srcb, nullptr, dst, (int)R, 256, 1024);
    }
}